// Round 7
// baseline (108.803 us; speedup 1.0000x reference)
//
#include <hip/hip_runtime.h>
#include <stdint.h>

#define NB    128
#define NSTEP 63
#define DT    0.00390625f

typedef __attribute__((ext_vector_type(8))) short bf16x8;
typedef __attribute__((ext_vector_type(4))) float f32x4;
typedef __attribute__((ext_vector_type(2))) float f32x2;

union Frag { bf16x8 v; uint32_t u[4]; };

__device__ __forceinline__ short f2bf(float f) {
    uint32_t u = __float_as_uint(f);
    u += 0x7FFF + ((u >> 16) & 1);          // round-to-nearest-even
    return (short)(u >> 16);
}

__device__ __forceinline__ uint32_t pk_bf16(float lo, float hi) {
    uint32_t r;
    asm("v_cvt_pk_bf16_f32 %0, %1, %2" : "=v"(r) : "v"(lo), "v"(hi));
    return r;
}

// Pade [5/4] tanh (continued fraction truncated at 9), clamped to |x|<=4:
//   tanh x ~= x(z^2 + 105z + 945) / (15z^2 + 420z + 945), z = x^2.
// Max error 2.3e-3 (at |x|~4), below the bf16 quantization noise of the
// following pack. ONE TRANS (rcp) per value instead of exp+rcp (two).
__device__ __forceinline__ f32x2 tanh2_pade(f32x2 x) {
    f32x2 xc = __builtin_elementwise_min(
                   __builtin_elementwise_max(x, (f32x2)(-4.0f)), (f32x2)(4.0f));
    f32x2 z   = xc * xc;
    f32x2 num = __builtin_elementwise_fma(z + (f32x2)105.0f, z, (f32x2)945.0f) * xc;
    f32x2 den = __builtin_elementwise_fma(z, (f32x2)15.0f, (f32x2)420.0f);
    den       = __builtin_elementwise_fma(den, z, (f32x2)945.0f);
    f32x2 r = { __builtin_amdgcn_rcpf(den.x), __builtin_amdgcn_rcpf(den.y) };
    return num * r;
}

// Block = 128 threads = 2 waves = one 16-trajectory group.
// Wave w owns net pair {2w, 2w+1}: w=0 -> drift (a_re, a_im), w=1 ->
// diffusion (b_re, b_im). Per wave: GEMM1 swapped (8 MFMAs, 128 h-cols),
// Pade-tanh, GEMM2 swapped dense K=64 (4 MFMAs) -> own nets' outputs at
// this lane's dims 4g..4g+3 (feature+hidden permutations as R6, lane-local).
// Cross-pair exchange: 4x ds_write_b64 / ds_read_b64 (lane-consecutive,
// conflict-free), double-buffered, one barrier/step. Fixed fma nesting
// keeps both waves' replicated state bitwise identical.
__global__ __launch_bounds__(128, 2) void sde_2wave(
    const float* __restrict__ x_real, const float* __restrict__ x_imag,
    const float* __restrict__ params, const float* __restrict__ noise,
    const float* __restrict__ W1, const float* __restrict__ B1,
    const float* __restrict__ W2, const float* __restrict__ B2,
    float* __restrict__ out)
{
    __shared__ f32x2 xb[2][4][2][64];   // [dbuf][pair-idx][wave][lane]

    const int tid  = threadIdx.x;
    const int lane = tid & 63;
    const int l15  = lane & 15;
    const int g    = lane >> 4;
    const int w    = tid >> 6;          // 0: drift nets, 1: diffusion nets
    const int n    = blockIdx.x * 16 + l15;

    // ---- GEMM1 A-frags: 8 tiles = 2 nets x 4; h = 16*(t&3)+l15 within net
    //      2w+(t>>2); elem j -> permuted feature (j<4: Re[4g+j], else Im) ----
    Frag w1f[8];
    #pragma unroll
    for (int t = 0; t < 8; ++t) {
        const int net = 2 * w + (t >> 2);
        const int hn  = 16 * (t & 3) + l15;
        #pragma unroll
        for (int j = 0; j < 8; ++j) {
            const int jf = (j < 4) ? (4 * g + j) : (16 + 4 * g + (j - 4));
            w1f[t].v[j] = f2bf(W1[(net * 38 + 1 + jf) * 64 + hn]);
        }
    }

    // ---- GEMM2 A-frags: local net j (global 2w+j), row=l15=d ----
    Frag w2f[2][2];
    #pragma unroll
    for (int j2 = 0; j2 < 2; ++j2)
        #pragma unroll
        for (int kt = 0; kt < 2; ++kt)
            #pragma unroll
            for (int j = 0; j < 8; ++j) {
                const int hl = 16 * (2 * kt + (j >> 2)) + 4 * g + (j & 3);
                w2f[j2][kt].v[j] = f2bf(W2[((2 * w + j2) * 64 + hl) * 16 + l15]);
            }

    // ---- bias + t-coefficient at C-layout positions (raw, no scale) ----
    float pr[5];
    #pragma unroll
    for (int p = 0; p < 5; ++p) pr[p] = params[p];
    f32x4 biascur[8], wtdt[8];
    #pragma unroll
    for (int t = 0; t < 8; ++t) {
        const int net = 2 * w + (t >> 2);
        #pragma unroll
        for (int r = 0; r < 4; ++r) {
            const int h = 16 * (t & 3) + 4 * g + r;
            float b = B1[net * 64 + h];
            #pragma unroll
            for (int p = 0; p < 5; ++p)
                b = fmaf(pr[p], W1[(net * 38 + 33 + p) * 64 + h], b);
            biascur[t][r] = b;
            wtdt[t][r]    = DT * W1[(net * 38 + 0) * 64 + h];
        }
    }

    // ---- B2 C-in per local net ----
    f32x4 bc[2];
    #pragma unroll
    for (int j2 = 0; j2 < 2; ++j2)
        #pragma unroll
        for (int r = 0; r < 4; ++r) bc[j2][r] = B2[(2 * w + j2) * 16 + 4 * g + r];

    // ---- state: lane holds Re[4g..4g+3], Im[4g..4g+3] of traj n (replicated) ----
    const int xrow = n & (NB - 1);
    f32x4 sre = *reinterpret_cast<const f32x4*>(&x_real[xrow * 16 + 4 * g]);
    f32x4 sim = *reinterpret_cast<const f32x4*>(&x_imag[xrow * 16 + 4 * g]);

    const float* __restrict__ nsp = noise + (size_t)n * NSTEP;
    float dw = nsp[0];

    for (int s = 0; s < NSTEP; ++s) {
        const float dwn = nsp[(s + 1 < NSTEP) ? s + 1 : s];

        // state -> B-frag: slots 8g+j = (j<4 ? Re[4g+j] : Im[4g+j-4])
        Frag bx;
        bx.u[0] = pk_bf16(sre[0], sre[1]);
        bx.u[1] = pk_bf16(sre[2], sre[3]);
        bx.u[2] = pk_bf16(sim[0], sim[1]);
        bx.u[3] = pk_bf16(sim[2], sim[3]);

        // GEMM1: 8 MFMAs over this wave's two nets
        f32x4 acc[8];
        #pragma unroll
        for (int t = 0; t < 8; ++t)
            acc[t] = __builtin_amdgcn_mfma_f32_16x16x32_bf16(
                w1f[t].v, bx.v, biascur[t], 0, 0, 0);
        #pragma unroll
        for (int t = 0; t < 8; ++t) biascur[t] += wtdt[t];

        // tanh (Pade, 1 TRANS/value) + GEMM2 (dense K=64 per net)
        f32x4 o[2];
        #pragma unroll
        for (int j2 = 0; j2 < 2; ++j2) {
            o[j2] = bc[j2];
            #pragma unroll
            for (int kt = 0; kt < 2; ++kt) {
                const int T0 = 4 * j2 + 2 * kt;
                const f32x2 t0 = tanh2_pade((f32x2){acc[T0][0],     acc[T0][1]});
                const f32x2 t1 = tanh2_pade((f32x2){acc[T0][2],     acc[T0][3]});
                const f32x2 t2 = tanh2_pade((f32x2){acc[T0 + 1][0], acc[T0 + 1][1]});
                const f32x2 t3 = tanh2_pade((f32x2){acc[T0 + 1][2], acc[T0 + 1][3]});
                Frag pb;
                pb.u[0] = pk_bf16(t0.x, t0.y);  pb.u[1] = pk_bf16(t1.x, t1.y);
                pb.u[2] = pk_bf16(t2.x, t2.y);  pb.u[3] = pk_bf16(t3.x, t3.y);
                o[j2] = __builtin_amdgcn_mfma_f32_16x16x32_bf16(
                    w2f[j2][kt].v, pb.v, o[j2], 0, 0, 0);
            }
        }

        // ---- exchange with partner wave (conflict-free b64, dbuf, 1 barrier) ----
        const int db = s & 1;
        xb[db][0][w][lane] = (f32x2){o[0][0], o[0][1]};
        xb[db][1][w][lane] = (f32x2){o[0][2], o[0][3]};
        xb[db][2][w][lane] = (f32x2){o[1][0], o[1][1]};
        xb[db][3][w][lane] = (f32x2){o[1][2], o[1][3]};
        __syncthreads();
        const f32x2 q0 = xb[db][0][w ^ 1][lane];
        const f32x2 q1 = xb[db][1][w ^ 1][lane];
        const f32x2 q2 = xb[db][2][w ^ 1][lane];
        const f32x2 q3 = xb[db][3][w ^ 1][lane];
        const f32x4 oth0 = {q0.x, q0.y, q1.x, q1.y};
        const f32x4 oth1 = {q2.x, q2.y, q3.x, q3.y};

        // Euler-Maruyama, FIXED nesting (dw-term inner) -> bitwise-identical
        // replicated state in both waves
        const f32x4 dt4 = (f32x4)DT;
        const f32x4 dw4 = (f32x4)dw;
        if (w == 0) {   // mine = drift, other = diffusion
            sre = __builtin_elementwise_fma(dt4, o[0],
                  __builtin_elementwise_fma(dw4, oth0, sre));
            sim = __builtin_elementwise_fma(dt4, o[1],
                  __builtin_elementwise_fma(dw4, oth1, sim));
        } else {        // mine = diffusion, other = drift
            sre = __builtin_elementwise_fma(dt4, oth0,
                  __builtin_elementwise_fma(dw4, o[0], sre));
            sim = __builtin_elementwise_fma(dt4, oth1,
                  __builtin_elementwise_fma(dw4, o[1], sim));
        }
        dw = dwn;
    }

    // ---- write out (wave 0 only) ----
    if (w == 0) {
        *reinterpret_cast<f32x4*>(out + (size_t)n * 32 + 4 * g)      = sre;
        *reinterpret_cast<f32x4*>(out + (size_t)n * 32 + 16 + 4 * g) = sim;
    }
}

extern "C" void kernel_launch(void* const* d_in, const int* in_sizes, int n_in,
                              void* d_out, int out_size, void* d_ws, size_t ws_size,
                              hipStream_t stream) {
    const float* x_real = (const float*)d_in[0];
    const float* x_imag = (const float*)d_in[1];
    const float* params = (const float*)d_in[2];
    const float* noise  = (const float*)d_in[3];
    const float* W1     = (const float*)d_in[4];
    const float* B1     = (const float*)d_in[5];
    const float* W2     = (const float*)d_in[6];
    const float* B2     = (const float*)d_in[7];
    float* out = (float*)d_out;

    // 1024 blocks x 128 threads = 2048 waves = 2/SIMD; 16 traj per block
    sde_2wave<<<dim3(1024), dim3(128), 0, stream>>>(
        x_real, x_imag, params, noise, W1, B1, W2, B2, out);
}

// Round 8
// 97.518 us; speedup vs baseline: 1.1157x; 1.1157x over previous
//
#include <hip/hip_runtime.h>
#include <stdint.h>

#define NB    128
#define NSTEP 63
#define DT    0.00390625f

typedef __attribute__((ext_vector_type(8))) short bf16x8;
typedef __attribute__((ext_vector_type(4))) float f32x4;
typedef __attribute__((ext_vector_type(2))) float f32x2;

union Frag { bf16x8 v; uint32_t u[4]; };

__device__ __forceinline__ short f2bf(float f) {
    uint32_t u = __float_as_uint(f);
    u += 0x7FFF + ((u >> 16) & 1);          // round-to-nearest-even
    return (short)(u >> 16);
}

__device__ __forceinline__ uint32_t pk_bf16(float lo, float hi) {
    uint32_t r;
    asm("v_cvt_pk_bf16_f32 %0, %1, %2" : "=v"(r) : "v"(lo), "v"(hi));
    return r;
}

// Pade [5/4] tanh (continued fraction truncated), clamped to |x|<=4:
//   tanh x ~= x(z^2 + 105z + 945) / (15z^2 + 420z + 945), z = x^2.
// Max error 2.3e-3, below bf16 pack quantization. ONE TRANS (rcp) per value
// instead of exp+rcp (two) -> halves the TRANS-pipe burst per step.
// Numerics proven in round 7 (absmax 0.0156, same as exp version).
__device__ __forceinline__ f32x2 tanh2_pade(f32x2 x) {
    f32x2 xc = __builtin_elementwise_min(
                   __builtin_elementwise_max(x, (f32x2)(-4.0f)), (f32x2)(4.0f));
    f32x2 z   = xc * xc;
    f32x2 num = __builtin_elementwise_fma(z + (f32x2)105.0f, z, (f32x2)945.0f) * xc;
    f32x2 den = __builtin_elementwise_fma(z, (f32x2)15.0f, (f32x2)420.0f);
    den       = __builtin_elementwise_fma(den, z, (f32x2)945.0f);
    f32x2 r = { __builtin_amdgcn_rcpf(den.x), __builtin_amdgcn_rcpf(den.y) };
    return num * r;
}

// Round-4 structure (best so far: 83.4 us), tanh swapped exp->Pade.
// Block = 256 threads = 4 waves = one 16-trajectory group; wave wv owns net
// wv. GEMM1 (swapped): wave's 64 hidden cols, 4 MFMAs; GEMM2 (swapped,
// dense, K=64): net's 16 outputs, 2 MFMAs. Hidden-order permutation makes
// GEMM1's C-layout registers bit-identical to GEMM2's B-fragment slots.
// Cross-net output exchange via double-buffered LDS, 1 barrier/step.
__global__ __launch_bounds__(256, 4) void sde_mfma4p(
    const float* __restrict__ x_real, const float* __restrict__ x_imag,
    const float* __restrict__ params, const float* __restrict__ noise,
    const float* __restrict__ W1, const float* __restrict__ B1,
    const float* __restrict__ W2, const float* __restrict__ B2,
    float* __restrict__ out)
{
    // [dbuf][net 4][traj 16][20 floats: d 0..15 used, pad 4]
    __shared__ __attribute__((aligned(16))) float xbuf[2][4][16][20];

    const int tid  = threadIdx.x;
    const int lane = tid & 63;
    const int l15  = lane & 15;
    const int g    = lane >> 4;
    const int wv   = tid >> 6;          // net index 0..3

    // ---- GEMM1 A-frags: tile t, row=l15 -> h = 16t + l15 (within net wv),
    //      elem j -> state feature 8g + j; RAW (no scale - Pade tanh) ----
    Frag w1f[4];
    #pragma unroll
    for (int t = 0; t < 4; ++t) {
        const int h = 16 * t + l15;
        #pragma unroll
        for (int j = 0; j < 8; ++j)
            w1f[t].v[j] = f2bf(W1[(wv * 38 + 1 + 8 * g + j) * 64 + h]);
    }

    // ---- GEMM2 A-frags: row=l15=d, elem j -> h_local = 16*(2kt+(j>>2)) + 4g + (j&3) ----
    Frag w2f[2];
    #pragma unroll
    for (int kt = 0; kt < 2; ++kt) {
        #pragma unroll
        for (int j = 0; j < 8; ++j) {
            const int hl = 16 * (2 * kt + (j >> 2)) + 4 * g + (j & 3);
            w2f[kt].v[j] = f2bf(W2[(wv * 64 + hl) * 16 + l15]);
        }
    }

    // ---- bias + t-coefficient at C-layout positions (raw) ----
    float pr[5];
    #pragma unroll
    for (int p = 0; p < 5; ++p) pr[p] = params[p];
    f32x4 biascur[4], wtdt[4];
    #pragma unroll
    for (int t = 0; t < 4; ++t) {
        #pragma unroll
        for (int r = 0; r < 4; ++r) {
            const int h = 16 * t + 4 * g + r;
            float b = B1[wv * 64 + h];
            #pragma unroll
            for (int p = 0; p < 5; ++p)
                b = fmaf(pr[p], W1[(wv * 38 + 33 + p) * 64 + h], b);
            biascur[t][r] = b;
            wtdt[t][r]    = DT * W1[(wv * 38 + 0) * 64 + h];
        }
    }

    // ---- B2 C-in: row 4g+r = output dim d ----
    f32x4 bc;
    #pragma unroll
    for (int r = 0; r < 4; ++r) bc[r] = B2[wv * 16 + 4 * g + r];

    // ---- state: lane holds comps 8g..8g+7 of traj n (replicated across waves) ----
    const int n    = blockIdx.x * 16 + l15;
    const int xrow = n & (NB - 1);
    const float* __restrict__ xsrc = (g < 2) ? x_real : x_imag;
    float st[8];
    #pragma unroll
    for (int i = 0; i < 8; ++i) st[i] = xsrc[xrow * 16 + (g & 1) * 8 + i];

    const float* __restrict__ nsp = noise + (size_t)n * NSTEP;
    float dw = nsp[0];

    float* wrp           = &xbuf[0][wv][l15][4 * g];
    const float* rd_dr   = &xbuf[0][g >> 1][l15][8 * (g & 1)];
    const float* rd_df   = &xbuf[0][2 + (g >> 1)][l15][8 * (g & 1)];
    const int dstep = 4 * 16 * 20;   // floats per dbuf half

    for (int s = 0; s < NSTEP; ++s) {
        const float dwn = nsp[(s + 1 < NSTEP) ? s + 1 : s];

        // state -> bf16 B-fragment (k-slot 8g+j = component 8g+j)
        Frag bx;
        bx.u[0] = pk_bf16(st[0], st[1]);
        bx.u[1] = pk_bf16(st[2], st[3]);
        bx.u[2] = pk_bf16(st[4], st[5]);
        bx.u[3] = pk_bf16(st[6], st[7]);

        // GEMM1: 4 MFMAs, C-in = bias + t*w_t
        f32x4 acc[4];
        #pragma unroll
        for (int t = 0; t < 4; ++t)
            acc[t] = __builtin_amdgcn_mfma_f32_16x16x32_bf16(
                w1f[t].v, bx.v, biascur[t], 0, 0, 0);
        #pragma unroll
        for (int t = 0; t < 4; ++t) biascur[t] += wtdt[t];

        // GEMM2: K=64 over own net's hidden, output = own net's 16 dims
        f32x4 o = bc;
        #pragma unroll
        for (int kt = 0; kt < 2; ++kt) {
            const f32x2 t0 = tanh2_pade((f32x2){acc[2 * kt][0],     acc[2 * kt][1]});
            const f32x2 t1 = tanh2_pade((f32x2){acc[2 * kt][2],     acc[2 * kt][3]});
            const f32x2 t2 = tanh2_pade((f32x2){acc[2 * kt + 1][0], acc[2 * kt + 1][1]});
            const f32x2 t3 = tanh2_pade((f32x2){acc[2 * kt + 1][2], acc[2 * kt + 1][3]});
            Frag pb;
            pb.u[0] = pk_bf16(t0.x, t0.y);  pb.u[1] = pk_bf16(t1.x, t1.y);
            pb.u[2] = pk_bf16(t2.x, t2.y);  pb.u[3] = pk_bf16(t3.x, t3.y);
            o = __builtin_amdgcn_mfma_f32_16x16x32_bf16(w2f[kt].v, pb.v, o, 0, 0, 0);
        }

        // ---- exchange: write own net's 4 outputs, read all 4 nets ----
        const int db = s & 1;
        *reinterpret_cast<f32x4*>(wrp + db * dstep) = o;
        __syncthreads();
        const float* dp = rd_dr + db * dstep;
        const float* fp = rd_df + db * dstep;
        const f32x4 dr0 = *reinterpret_cast<const f32x4*>(dp);
        const f32x4 dr1 = *reinterpret_cast<const f32x4*>(dp + 4);
        const f32x4 df0 = *reinterpret_cast<const f32x4*>(fp);
        const f32x4 df1 = *reinterpret_cast<const f32x4*>(fp + 4);

        // Euler-Maruyama, packed fma
        const f32x4 dt4 = (f32x4)DT;
        const f32x4 dw4 = (f32x4)dw;
        f32x4 stlo = {st[0], st[1], st[2], st[3]};
        f32x4 sthi = {st[4], st[5], st[6], st[7]};
        stlo = __builtin_elementwise_fma(dt4, dr0,
               __builtin_elementwise_fma(dw4, df0, stlo));
        sthi = __builtin_elementwise_fma(dt4, dr1,
               __builtin_elementwise_fma(dw4, df1, sthi));
        #pragma unroll
        for (int i = 0; i < 4; ++i) { st[i] = stlo[i]; st[i + 4] = sthi[i]; }
        dw = dwn;
    }

    // ---- write out (wave 0 only): lane holds comps 8g..8g+7 of traj n ----
    if (wv == 0) {
        float4* op = reinterpret_cast<float4*>(out + (size_t)n * 32 + 8 * g);
        op[0] = make_float4(st[0], st[1], st[2], st[3]);
        op[1] = make_float4(st[4], st[5], st[6], st[7]);
    }
}

extern "C" void kernel_launch(void* const* d_in, const int* in_sizes, int n_in,
                              void* d_out, int out_size, void* d_ws, size_t ws_size,
                              hipStream_t stream) {
    const float* x_real = (const float*)d_in[0];
    const float* x_imag = (const float*)d_in[1];
    const float* params = (const float*)d_in[2];
    const float* noise  = (const float*)d_in[3];
    const float* W1     = (const float*)d_in[4];
    const float* B1     = (const float*)d_in[5];
    const float* W2     = (const float*)d_in[6];
    const float* B2     = (const float*)d_in[7];
    float* out = (float*)d_out;

    // 1024 blocks x 256 threads: 4 waves/block, one 16-traj group per block
    sde_mfma4p<<<dim3(1024), dim3(256), 0, stream>>>(
        x_real, x_imag, params, noise, W1, B1, W2, B2, out);
}